// Round 8
// baseline (351.799 us; speedup 1.0000x reference)
//
#include <hip/hip_runtime.h>
#include <math.h>

#define F_NODES 16384
#define DEG 8
#define E_TOT (F_NODES * DEG)   // 131072
#define B 64
#define H 16
#define LAYERS 10

#define NPB 16                  // nodes per block
#define TPB 256                 // 4 waves; wave owns 4 nodes
#define GRIDN (F_NODES / NPB)   // 1024 blocks = 4/CU

typedef unsigned short bf16_t;

__device__ __forceinline__ bf16_t f32_to_bf16(float f)
{
    unsigned u = __float_as_uint(f);
    u = (u + 0x7FFFu + ((u >> 16) & 1u)) >> 16;   // RNE
    return (bf16_t)u;
}
__device__ __forceinline__ float bf16_to_f32(bf16_t h)
{
    return __uint_as_float((unsigned)h << 16);
}
__device__ __forceinline__ float bfu_lo(unsigned u) { return __uint_as_float(u << 16); }
__device__ __forceinline__ float bfu_hi(unsigned u) { return __uint_as_float(u & 0xFFFF0000u); }

// ---------------------------------------------------------------------------
// Transpose x0 (B, E) fp32 -> x0T16 (E, B) bf16. Row e = 64 bf16 = 128 B.
// ---------------------------------------------------------------------------
__global__ __launch_bounds__(256) void transpose_in_kernel(
    const float* __restrict__ x0, bf16_t* __restrict__ xT16)
{
    __shared__ float tile[64 * 65];
    const int e0 = blockIdx.x * 64;
    const int c  = threadIdx.x & 63;
    const int r  = threadIdx.x >> 6;

    #pragma unroll
    for (int i = 0; i < 16; ++i) {
        const int b = r + i * 4;
        tile[c * 65 + b] = x0[(size_t)b * E_TOT + e0 + c];
    }
    __syncthreads();
    const int b = threadIdx.x & 63;
    #pragma unroll
    for (int i = 0; i < 16; ++i) {
        const int el = r + i * 4;
        xT16[(size_t)(e0 + el) * B + b] = f32_to_bf16(tile[el * 65 + b]);
    }
}

// Pack W1/W2 fp32 -> bf16 pairs (one dword = 2 consecutive weights).
__global__ __launch_bounds__(256) void pack_weights_kernel(
    const float* __restrict__ W1, const float* __restrict__ W2,
    unsigned* __restrict__ W1b, unsigned* __restrict__ W2b)
{
    const int i = blockIdx.x * 256 + threadIdx.x;
    float2 a = ((const float2*)W1)[i];
    W1b[i] = (unsigned)f32_to_bf16(a.x) | ((unsigned)f32_to_bf16(a.y) << 16);
    float2 c = ((const float2*)W2)[i];
    W2b[i] = (unsigned)f32_to_bf16(c.x) | ((unsigned)f32_to_bf16(c.y) << 16);
}

__device__ __forceinline__ float fast_elu(float x)
{
    float e = __builtin_amdgcn_exp2f(x * 1.44269504088896340736f) - 1.0f;
    return x > 0.0f ? x : e;
}

// ---------------------------------------------------------------------------
// One GSNN layer, LDS-staged so ALL global traffic is 16 B/lane (dwordx4):
//  P1: coop-load 128 gathered z rows (row k=P[e], 128 B = 8 lanes x uint4)
//      + the block's contiguous 16 KB residual region            -> LDS
//  P2: per-lane ds_read_u16 (stride 2 B: free 2-way aliasing) -> registers
//  P3: MLP per node (bf16 weights via wave-uniform s_load, fp32 acc)
//  P4: outputs -> LDS bf16 (overwrites own node's gather tile; same-wave
//      hazard only, lockstep-safe)
//  P5: coop-store the block's 16 KB output region, fully sequential
// z stays NATURAL node-major (E,B): every layer gathers via P identically.
// ---------------------------------------------------------------------------
template <bool FINAL>
__global__ __launch_bounds__(TPB) void layer_kernel(
    const bf16_t*   __restrict__ zsrc,   // (E, B) bf16 (x0T16 for layer 0)
    const bf16_t*   __restrict__ x0T16,  // (E, B) bf16 residual
    const unsigned* __restrict__ W1b,    // (F, H, DEG/2) packed bf16
    const float*    __restrict__ b1,     // (F, H)
    const unsigned* __restrict__ W2b,    // (F, DEG, H/2) packed bf16
    const float*    __restrict__ b2,     // (F, DEG)
    const int*      __restrict__ in_ixs, // (F, DEG) = P
    bf16_t* __restrict__ zout,           // (E, B) bf16
    float*  __restrict__ out)            // (B, E) fp32 if FINAL
{
    __shared__ uint4 ldsG4[NPB * 8 * 8];   // 16 KB gather/out tiles [j][p]
    __shared__ uint4 ldsR4[NPB * 8 * 8];   // 16 KB residual tiles

    const int t   = threadIdx.x;
    const int f0  = (int)blockIdx.x * NPB;
    const size_t e0 = (size_t)f0 * DEG;            // first row of this block

    // ---- P1: cooperative 16 B/lane loads ----
    const uint4* resp = (const uint4*)(x0T16 + e0 * B);
    #pragma unroll
    for (int rnd = 0; rnd < 4; ++rnd) {
        const int slot = rnd * TPB + t;            // 0..1023
        const int j = slot >> 3;                   // local row 0..127
        const int p = slot & 7;                    // 16B part within row
        const int k = in_ixs[e0 + j];              // gathered source row
        ldsG4[slot] = ((const uint4*)(zsrc + (size_t)k * B))[p];
        ldsR4[slot] = resp[slot];
    }
    __syncthreads();

    // ---- P2..P4: per-wave MLP over 4 nodes ----
    const int lane = t & 63;
    const int wv   = t >> 6;
    const unsigned short* ldsG = (const unsigned short*)ldsG4;
    const unsigned short* ldsR = (const unsigned short*)ldsR4;

    #pragma unroll
    for (int n = 0; n < 4; ++n) {
        const int q = wv * 4 + n;                  // local node 0..15
        const int f = __builtin_amdgcn_readfirstlane(f0 + q);

        float g[DEG], r[DEG];
        #pragma unroll
        for (int d = 0; d < DEG; ++d) {
            g[d] = bf16_to_f32(ldsG[(q * DEG + d) * B + lane]);
            r[d] = bf16_to_f32(ldsR[(q * DEG + d) * B + lane]);
        }

        const unsigned* w1 = W1b + f * (H * DEG / 2);
        const float*   bb1 = b1 + f * H;
        float h[H];
        #pragma unroll
        for (int j = 0; j < H; ++j) {
            float acc = bb1[j];
            #pragma unroll
            for (int dp = 0; dp < DEG / 2; ++dp) {
                const unsigned u = w1[j * (DEG / 2) + dp];
                acc = fmaf(bfu_lo(u), g[2 * dp],     acc);
                acc = fmaf(bfu_hi(u), g[2 * dp + 1], acc);
            }
            h[j] = fast_elu(acc);
        }

        const unsigned* w2 = W2b + f * (DEG * H / 2);
        const float*   bb2 = b2 + f * DEG;
        float o[DEG];
        #pragma unroll
        for (int d = 0; d < DEG; ++d) {
            float acc = bb2[d];
            #pragma unroll
            for (int jp = 0; jp < H / 2; ++jp) {
                const unsigned u = w2[d * (H / 2) + jp];
                acc = fmaf(bfu_lo(u), h[2 * jp],     acc);
                acc = fmaf(bfu_hi(u), h[2 * jp + 1], acc);
            }
            o[d] = acc + r[d];
        }

        if (FINAL) {
            // natural (B, E) fp32: lane b owns 8 consecutive floats
            float4 v0 = make_float4(o[0], o[1], o[2], o[3]);
            float4 v1 = make_float4(o[4], o[5], o[6], o[7]);
            float4* dst = (float4*)(out + (size_t)lane * E_TOT + f * DEG);
            dst[0] = v0;
            dst[1] = v1;
        } else {
            // write output into own node's gather tile (lockstep-safe)
            unsigned short* ldsW = (unsigned short*)ldsG4;
            #pragma unroll
            for (int d = 0; d < DEG; ++d)
                ldsW[(q * DEG + d) * B + lane] = f32_to_bf16(o[d]);
        }
    }

    // ---- P5: cooperative sequential 16 B/lane stores ----
    if (!FINAL) {
        __syncthreads();
        uint4* dst = (uint4*)(zout + e0 * B);
        #pragma unroll
        for (int rnd = 0; rnd < 4; ++rnd) {
            const int slot = rnd * TPB + t;
            dst[slot] = ldsG4[slot];
        }
    }
}

extern "C" void kernel_launch(void* const* d_in, const int* in_sizes, int n_in,
                              void* d_out, int out_size, void* d_ws, size_t ws_size,
                              hipStream_t stream)
{
    const float* x0     = (const float*)d_in[0];
    const float* W1     = (const float*)d_in[1];
    const float* b1     = (const float*)d_in[2];
    const float* W2     = (const float*)d_in[3];
    const float* b2     = (const float*)d_in[4];
    const int*   in_ixs = (const int*)d_in[5];
    float* out = (float*)d_out;

    const size_t NEL = (size_t)E_TOT * B;        // 8.39M elements
    bf16_t*   x0T16 = (bf16_t*)d_ws;             // 16 MB
    bf16_t*   zA    = x0T16 + NEL;               // 16 MB
    bf16_t*   zB    = zA + NEL;                  // 16 MB
    unsigned* W1b   = (unsigned*)(zB + NEL);     // 4.2 MB
    unsigned* W2b   = W1b + F_NODES * H * DEG / 2;

    transpose_in_kernel<<<E_TOT / 64, 256, 0, stream>>>(x0, x0T16);
    pack_weights_kernel<<<F_NODES * H * DEG / 2 / 256, 256, 0, stream>>>(
        W1, W2, W1b, W2b);

    // layer 0 gathers from x0T16; all mid layers gather from previous z
    layer_kernel<false><<<GRIDN, TPB, 0, stream>>>(
        x0T16, x0T16, W1b, b1, W2b, b2, in_ixs, zA, nullptr);

    const bf16_t* cur = zA;
    bf16_t* nxt = zB;
    for (int l = 1; l < LAYERS - 1; ++l) {
        layer_kernel<false><<<GRIDN, TPB, 0, stream>>>(
            cur, x0T16, W1b, b1, W2b, b2, in_ixs, nxt, nullptr);
        cur = nxt;
        nxt = (nxt == zA) ? zB : zA;
    }

    layer_kernel<true><<<GRIDN, TPB, 0, stream>>>(
        cur, x0T16, W1b, b1, W2b, b2, in_ixs, nullptr, out);
}